// Round 3
// baseline (542.150 us; speedup 1.0000x reference)
//
#include <hip/hip_runtime.h>
#include <cstdint>
#include <cstddef>

#define T_SEQ 2048
#define B_SZ  2
#define EMB   2048
#define NH    16
#define NKV   4
#define HD    128
#define KVD   512
#define QKVN  3072
#define MROWS (B_SZ*T_SEQ)

typedef __bf16 bf16x8 __attribute__((ext_vector_type(8)));
typedef float  f32x4  __attribute__((ext_vector_type(4)));
typedef short  s16x8  __attribute__((ext_vector_type(8)));
typedef unsigned short u16;

__device__ __forceinline__ u16 f2b(float f) {
  uint32_t u = __builtin_bit_cast(uint32_t, f);
  u += 0x7fffu + ((u >> 16) & 1u);      // RNE
  return (u16)(u >> 16);
}
__device__ __forceinline__ float b2f(u16 h) {
  return __builtin_bit_cast(float, (uint32_t)h << 16);
}
__device__ __forceinline__ bf16x8 ld_bf8(const u16* p) {
  return __builtin_bit_cast(bf16x8, *(const s16x8*)p);
}
__device__ __forceinline__ void glds16(const void* g, void* l) {
  __builtin_amdgcn_global_load_lds((const __attribute__((address_space(1))) void*)g,
                                   (__attribute__((address_space(3))) void*)l, 16, 0, 0);
}

// ---------------- fp32 -> bf16 elementwise ----------------
__global__ void cvt_x_kernel(const float4* __restrict__ x, ushort4* __restrict__ xb, int n4) {
  int i = blockIdx.x*blockDim.x + threadIdx.x;
  if (i >= n4) return;
  float4 v = x[i];
  ushort4 o;
  o.x = f2b(v.x); o.y = f2b(v.y); o.z = f2b(v.z); o.w = f2b(v.w);
  xb[i] = o;
}

// ---------------- fp32 (R x C) -> bf16 transposed (C x R) ----------------
__global__ void transpose_w_kernel(const float* __restrict__ in, u16* __restrict__ out,
                                   int R, int C) {
  __shared__ float tile[32][33];
  int c0 = blockIdx.x*32, r0 = blockIdx.y*32;
  int tx = threadIdx.x, ty = threadIdx.y;
#pragma unroll
  for (int i = 0; i < 32; i += 8)
    tile[ty+i][tx] = in[(size_t)(r0+ty+i)*C + c0+tx];
  __syncthreads();
#pragma unroll
  for (int i = 0; i < 32; i += 8)
    out[(size_t)(c0+ty+i)*R + r0+tx] = f2b(tile[tx][ty+i]);
}

// ---------------- bf16 GEMM: C(MxN) = A(MxK) * Bt(NxK)^T (+bias) ----------------
template<bool BF16_OUT>
__global__ __launch_bounds__(256) void gemm_kernel(const u16* __restrict__ A,
        const u16* __restrict__ Bt, const float* __restrict__ bias,
        void* __restrict__ Cout, int M, int N, int K) {
  __shared__ u16 As[128*32];
  __shared__ u16 Bs[128*32];
  const int tid = threadIdx.x;
  const int w = tid >> 6, lane = tid & 63;
  const int quad = lane >> 4, lc = lane & 15;
  const int m0 = blockIdx.y*128, n0 = blockIdx.x*128;
  const int wm = (w >> 1)*64, wn = (w & 1)*64;
  f32x4 acc[4][4] = {};
  for (int k0 = 0; k0 < K; k0 += 32) {
    __syncthreads();
#pragma unroll
    for (int r = 0; r < 2; ++r) {
      int c = r*256 + tid;             // 16B chunk id, 0..511
      int row = c >> 2, off = (c & 3)*8;
      glds16(A  + (size_t)(m0+row)*K + k0 + off, As + (size_t)(r*256 + w*64)*8);
      glds16(Bt + (size_t)(n0+row)*K + k0 + off, Bs + (size_t)(r*256 + w*64)*8);
    }
    __syncthreads();
    bf16x8 af[4], bfr[4];
#pragma unroll
    for (int i = 0; i < 4; ++i) af[i]  = ld_bf8(As + (wm + i*16 + lc)*32 + quad*8);
#pragma unroll
    for (int j = 0; j < 4; ++j) bfr[j] = ld_bf8(Bs + (wn + j*16 + lc)*32 + quad*8);
#pragma unroll
    for (int i = 0; i < 4; ++i)
#pragma unroll
      for (int j = 0; j < 4; ++j)
        acc[i][j] = __builtin_amdgcn_mfma_f32_16x16x32_bf16(af[i], bfr[j], acc[i][j], 0, 0, 0);
  }
#pragma unroll
  for (int j = 0; j < 4; ++j) {
    int col = n0 + wn + j*16 + lc;
    float bv = BF16_OUT ? bias[col] : 0.0f;
#pragma unroll
    for (int i = 0; i < 4; ++i) {
      int rowb = m0 + wm + i*16 + quad*4;
#pragma unroll
      for (int r = 0; r < 4; ++r) {
        float v = acc[i][j][r] + bv;
        if (BF16_OUT) ((u16*)Cout)[(size_t)(rowb+r)*N + col] = f2b(v);
        else          ((float*)Cout)[(size_t)(rowb+r)*N + col] = v;
      }
    }
  }
}

// ---------------- RoPE on K and V (reference ropes V too, not Q) ----------------
__global__ void rope_kernel(const u16* __restrict__ qkv, const float* __restrict__ fc,
                            const float* __restrict__ fs, u16* __restrict__ kout,
                            u16* __restrict__ vout) {
  int tid = threadIdx.x;
  int row = blockIdx.x;             // b*T + t
  int i = tid & 63, kv = tid >> 6;  // pair index, kv head
  int t = row & (T_SEQ-1);
  const u16* p = qkv + (size_t)row*QKVN + EMB + kv*HD + 2*i;
  float ka = b2f(p[0]),   kb = b2f(p[1]);
  float va = b2f(p[KVD]), vb = b2f(p[KVD+1]);
  float c = fc[t*64+i], s = fs[t*64+i];
  size_t ob = (size_t)row*KVD + kv*HD + 2*i;
  kout[ob]   = f2b(ka*c - kb*s);
  kout[ob+1] = f2b(ka*s + kb*c);
  vout[ob]   = f2b(va*c - vb*s);
  vout[ob+1] = f2b(va*s + vb*c);
}

// ---------------- V (b,t,kv,d) -> Vt (b,kv,d,t) ----------------
__global__ void transpose_v_kernel(const u16* __restrict__ vb, u16* __restrict__ vtb) {
  __shared__ u16 tile[32][33];
  int bkv = blockIdx.z;
  int b = bkv >> 2, kv = bkv & 3;
  int d0 = blockIdx.y*32, t0 = blockIdx.x*32;
  int tx = threadIdx.x, ty = threadIdx.y;
#pragma unroll
  for (int i = 0; i < 32; i += 8)
    tile[ty+i][tx] = vb[(size_t)(b*T_SEQ + t0+ty+i)*KVD + kv*HD + d0 + tx];
  __syncthreads();
#pragma unroll
  for (int i = 0; i < 32; i += 8)
    vtb[(size_t)(bkv*HD + d0+ty+i)*T_SEQ + t0 + tx] = tile[tx][ty+i];
}

// ---------------- flash attention v3: 4-wave split-K per 32-query tile ----------
// One 256-thread block per (b, h, 32-query tile). Wave w handles key tiles
// k0 = w*64 + i*256 (interleaved). Fixed m=0 makes partial softmax sums linear,
// so waves combine with a single LDS ds_add_f32 pass at the end (2 barriers,
// not per-iteration). K-loop itself is barrier-free; K/V frags come straight
// from global (L2-served, XCD-pinned via blockIdx&7). Per-wave P C->A layout
// roundtrip via LDS relies on in-order intra-wave DS execution (no asm
// memory clobber, so the scheduler can hoist V loads over the softmax VALU).
__global__ __launch_bounds__(256) void flash_kernel(const u16* __restrict__ qkv,
    const u16* __restrict__ kb, const u16* __restrict__ vtb, u16* __restrict__ yb) {
  constexpr int PP = 72;                 // P pitch (elems)
  constexpr int OP = 132;                // O-combine pitch (floats): 2-way-free banks
  __shared__ union {
    u16 Ps[4][32*PP];                                  // 18432 B, used in K-loop
    struct { float O[32*OP]; float L[32]; } c;         // 17024 B, used in epilogue
  } sm;
  const int tid = threadIdx.x;
  const int w = tid >> 6, lane = tid & 63;
  const int quad = lane >> 4, lc = lane & 15;
  const int bkv = blockIdx.x & 7;        // XCD-pinned (b,kv)
  const int rr_ = blockIdx.x >> 3;       // 0..255
  const int b = bkv >> 2, kv = bkv & 3;
  const int h = kv*4 + (rr_ & 3);
  const int qt = 63 - (rr_ >> 2);        // heavy tiles dispatch first
  const int qbase = qt*32;

  // Q fragments (A-layout) for 32 queries; no RoPE on Q
  bf16x8 qf[2][4];
#pragma unroll
  for (int hf = 0; hf < 2; ++hf) {
    const u16* qp = qkv + (size_t)(b*T_SEQ + qbase + hf*16 + lc)*QKVN + h*HD + quad*8;
#pragma unroll
    for (int ks = 0; ks < 4; ++ks) qf[hf][ks] = ld_bf8(qp + ks*32);
  }

  f32x4 o[2][8] = {};
  float rs[2][4] = {{0.f,0.f,0.f,0.f},{0.f,0.f,0.f,0.f}};
  const u16* kbase = kb  + (size_t)b*T_SEQ*KVD + kv*HD;
  const u16* vbase = vtb + (size_t)bkv*HD*T_SEQ;
  const int nk = qbase + 32;
  const float cs = 0.08838834764831845f * 1.4426950408889634f;  // scale * log2(e)
  u16* pw = sm.Ps[w];
  bool worked = false;

  for (int k0 = w*64; k0 < nk; k0 += 256) {
    worked = true;
    // S = Q K^T : 32 queries x 64 keys
    f32x4 sc[2][4] = {};
#pragma unroll
    for (int nt = 0; nt < 4; ++nt) {
      const u16* kp = kbase + (size_t)(k0 + nt*16 + lc)*KVD + quad*8;
      bf16x8 kf[4];
#pragma unroll
      for (int ks = 0; ks < 4; ++ks) kf[ks] = ld_bf8(kp + ks*32);
#pragma unroll
      for (int hf = 0; hf < 2; ++hf)
#pragma unroll
        for (int ks = 0; ks < 4; ++ks)
          sc[hf][nt] = __builtin_amdgcn_mfma_f32_16x16x32_bf16(qf[hf][ks], kf[ks], sc[hf][nt], 0, 0, 0);
    }

    // softmax (m=0): p = exp2(s*cs), causal-masked only on diagonal tiles
    if (k0 + 63 > qbase) {               // wave-uniform: tile touches the diagonal
#pragma unroll
      for (int hf = 0; hf < 2; ++hf) {
        int qrow = qbase + hf*16 + quad*4;
#pragma unroll
        for (int nt = 0; nt < 4; ++nt) {
          int key = k0 + nt*16 + lc;
#pragma unroll
          for (int r = 0; r < 4; ++r) {
            float p = (key <= qrow + r) ? exp2f(sc[hf][nt][r]*cs) : 0.0f;
            rs[hf][r] += p;
            pw[(hf*16 + quad*4 + r)*PP + nt*16 + lc] = f2b(p);
          }
        }
      }
    } else {
#pragma unroll
      for (int hf = 0; hf < 2; ++hf)
#pragma unroll
        for (int nt = 0; nt < 4; ++nt)
#pragma unroll
          for (int r = 0; r < 4; ++r) {
            float p = exp2f(sc[hf][nt][r]*cs);
            rs[hf][r] += p;
            pw[(hf*16 + quad*4 + r)*PP + nt*16 + lc] = f2b(p);
          }
    }

    // P: C-layout -> A-layout (intra-wave DS ops execute in order)
    bf16x8 pa[2][2];
#pragma unroll
    for (int hf = 0; hf < 2; ++hf)
#pragma unroll
      for (int ks = 0; ks < 2; ++ks)
        pa[hf][ks] = ld_bf8(pw + (hf*16 + lc)*PP + ks*32 + quad*8);

    // O += P V
#pragma unroll
    for (int j = 0; j < 8; ++j) {
      const u16* vp = vbase + (size_t)(j*16 + lc)*T_SEQ + k0 + quad*8;
      bf16x8 vf[2];
#pragma unroll
      for (int ks = 0; ks < 2; ++ks) vf[ks] = ld_bf8(vp + ks*32);
#pragma unroll
      for (int hf = 0; hf < 2; ++hf)
#pragma unroll
        for (int ks = 0; ks < 2; ++ks)
          o[hf][j] = __builtin_amdgcn_mfma_f32_16x16x32_bf16(pa[hf][ks], vf[ks], o[hf][j], 0, 0, 0);
    }
  }

  // ---- combine the 4 waves' partials (linear since m=0) ----
  __syncthreads();                       // all waves done with Ps
  for (int i = tid; i < 32*OP; i += 256) sm.c.O[i] = 0.f;
  if (tid < 32) sm.c.L[tid] = 0.f;
  __syncthreads();
  if (worked) {
#pragma unroll
    for (int hf = 0; hf < 2; ++hf)
#pragma unroll
      for (int r = 0; r < 4; ++r) {
        float v = rs[hf][r];
#pragma unroll
        for (int off2 = 8; off2 >= 1; off2 >>= 1)
          v += __shfl_xor(v, off2);
        if (lc == 0) atomicAdd(&sm.c.L[hf*16 + quad*4 + r], v);
#pragma unroll
        for (int j = 0; j < 8; ++j)
          atomicAdd(&sm.c.O[(hf*16 + quad*4 + r)*OP + j*16 + lc], o[hf][j][r]);
      }
  }
  __syncthreads();

  // store: 256 threads cover 32 q x (8 chunks of 16 d)
  {
    int q = tid >> 3, d0 = (tid & 7)*16;
    float inv = 1.0f / sm.c.L[q];
    const float* orow = sm.c.O + q*OP + d0;
    u16 outv[16];
#pragma unroll
    for (int i = 0; i < 16; ++i) outv[i] = f2b(orow[i]*inv);
    u16* dst = yb + (size_t)(b*T_SEQ + qbase + q)*EMB + h*HD + d0;
    *(s16x8*)dst       = *(s16x8*)outv;
    *(s16x8*)(dst + 8) = *(s16x8*)(outv + 8);
  }
}

extern "C" void kernel_launch(void* const* d_in, const int* in_sizes, int n_in,
                              void* d_out, int out_size, void* d_ws, size_t ws_size,
                              hipStream_t stream) {
  const float* x      = (const float*)d_in[0];
  const float* W_attn = (const float*)d_in[1];
  const float* b_attn = (const float*)d_in[2];
  const float* W_proj = (const float*)d_in[3];
  const float* fc     = (const float*)d_in[4];
  const float* fs     = (const float*)d_in[5];

  u16* ws   = (u16*)d_ws;
  u16* xb   = ws;                          // 8.39M elems  (later aliased by yb)
  u16* WaT  = xb   + (size_t)MROWS*EMB;    // 6.29M        (later aliased by WpT)
  u16* qkv  = WaT  + (size_t)QKVN*EMB;     // 12.58M
  u16* kbuf = qkv  + (size_t)MROWS*QKVN;   // 2.10M
  u16* vb   = kbuf + (size_t)MROWS*KVD;    // 2.10M
  u16* vtb  = vb   + (size_t)MROWS*KVD;    // 2.10M  -> total 67.1 MB
  u16* WpT  = WaT;   // W_attn^T dead after gemm1
  u16* yb   = xb;    // x_bf16 dead after gemm1
  float* out = (float*)d_out;

  cvt_x_kernel<<<(MROWS*EMB/4 + 255)/256, 256, 0, stream>>>(
      (const float4*)x, (ushort4*)xb, MROWS*EMB/4);
  transpose_w_kernel<<<dim3(QKVN/32, EMB/32), dim3(32, 8), 0, stream>>>(
      W_attn, WaT, EMB, QKVN);
  gemm_kernel<true><<<dim3(QKVN/128, MROWS/128), 256, 0, stream>>>(
      xb, WaT, b_attn, qkv, MROWS, QKVN, EMB);
  rope_kernel<<<MROWS, 256, 0, stream>>>(qkv, fc, fs, kbuf, vb);
  transpose_v_kernel<<<dim3(T_SEQ/32, HD/32, B_SZ*NKV), dim3(32, 8), 0, stream>>>(vb, vtb);
  transpose_w_kernel<<<dim3(EMB/32, EMB/32), dim3(32, 8), 0, stream>>>(
      W_proj, WpT, EMB, EMB);
  flash_kernel<<<dim3(B_SZ*NH*(T_SEQ/32)), 256, 0, stream>>>(qkv, kbuf, vtb, yb);
  gemm_kernel<false><<<dim3(EMB/128, MROWS/128), 256, 0, stream>>>(
      yb, WpT, nullptr, out, MROWS, EMB, EMB);
}

// Round 4
// 314.717 us; speedup vs baseline: 1.7227x; 1.7227x over previous
//
#include <hip/hip_runtime.h>
#include <cstdint>
#include <cstddef>

#define T_SEQ 2048
#define B_SZ  2
#define EMB   2048
#define NH    16
#define NKV   4
#define HD    128
#define KVD   512
#define QKVN  3072
#define MROWS (B_SZ*T_SEQ)

typedef __bf16 bf16x8 __attribute__((ext_vector_type(8)));
typedef float  f32x4  __attribute__((ext_vector_type(4)));
typedef short  s16x8  __attribute__((ext_vector_type(8)));
typedef unsigned short u16;

__device__ __forceinline__ u16 f2b(float f) {
  uint32_t u = __builtin_bit_cast(uint32_t, f);
  u += 0x7fffu + ((u >> 16) & 1u);      // RNE
  return (u16)(u >> 16);
}
__device__ __forceinline__ float b2f(u16 h) {
  return __builtin_bit_cast(float, (uint32_t)h << 16);
}
__device__ __forceinline__ bf16x8 ld_bf8(const u16* p) {
  return __builtin_bit_cast(bf16x8, *(const s16x8*)p);
}
__device__ __forceinline__ void glds16(const void* g, void* l) {
  __builtin_amdgcn_global_load_lds((const __attribute__((address_space(1))) void*)g,
                                   (__attribute__((address_space(3))) void*)l, 16, 0, 0);
}

// ---------------- fp32 -> bf16 elementwise ----------------
__global__ void cvt_x_kernel(const float4* __restrict__ x, ushort4* __restrict__ xb, int n4) {
  int i = blockIdx.x*blockDim.x + threadIdx.x;
  if (i >= n4) return;
  float4 v = x[i];
  ushort4 o;
  o.x = f2b(v.x); o.y = f2b(v.y); o.z = f2b(v.z); o.w = f2b(v.w);
  xb[i] = o;
}

// ---------------- fp32 (R x C) -> bf16 transposed (C x R) ----------------
__global__ void transpose_w_kernel(const float* __restrict__ in, u16* __restrict__ out,
                                   int R, int C) {
  __shared__ float tile[32][33];
  int c0 = blockIdx.x*32, r0 = blockIdx.y*32;
  int tx = threadIdx.x, ty = threadIdx.y;
#pragma unroll
  for (int i = 0; i < 32; i += 8)
    tile[ty+i][tx] = in[(size_t)(r0+ty+i)*C + c0+tx];
  __syncthreads();
#pragma unroll
  for (int i = 0; i < 32; i += 8)
    out[(size_t)(c0+ty+i)*R + r0+tx] = f2b(tile[tx][ty+i]);
}

// ---------------- bf16 GEMM: C(MxN) = A(MxK) * Bt(NxK)^T (+bias) ----------------
template<bool BF16_OUT>
__global__ __launch_bounds__(256) void gemm_kernel(const u16* __restrict__ A,
        const u16* __restrict__ Bt, const float* __restrict__ bias,
        void* __restrict__ Cout, int M, int N, int K) {
  __shared__ u16 As[128*32];
  __shared__ u16 Bs[128*32];
  const int tid = threadIdx.x;
  const int w = tid >> 6, lane = tid & 63;
  const int quad = lane >> 4, lc = lane & 15;
  const int m0 = blockIdx.y*128, n0 = blockIdx.x*128;
  const int wm = (w >> 1)*64, wn = (w & 1)*64;
  f32x4 acc[4][4] = {};
  for (int k0 = 0; k0 < K; k0 += 32) {
    __syncthreads();
#pragma unroll
    for (int r = 0; r < 2; ++r) {
      int c = r*256 + tid;             // 16B chunk id, 0..511
      int row = c >> 2, off = (c & 3)*8;
      glds16(A  + (size_t)(m0+row)*K + k0 + off, As + (size_t)(r*256 + w*64)*8);
      glds16(Bt + (size_t)(n0+row)*K + k0 + off, Bs + (size_t)(r*256 + w*64)*8);
    }
    __syncthreads();
    bf16x8 af[4], bfr[4];
#pragma unroll
    for (int i = 0; i < 4; ++i) af[i]  = ld_bf8(As + (wm + i*16 + lc)*32 + quad*8);
#pragma unroll
    for (int j = 0; j < 4; ++j) bfr[j] = ld_bf8(Bs + (wn + j*16 + lc)*32 + quad*8);
#pragma unroll
    for (int i = 0; i < 4; ++i)
#pragma unroll
      for (int j = 0; j < 4; ++j)
        acc[i][j] = __builtin_amdgcn_mfma_f32_16x16x32_bf16(af[i], bfr[j], acc[i][j], 0, 0, 0);
  }
#pragma unroll
  for (int j = 0; j < 4; ++j) {
    int col = n0 + wn + j*16 + lc;
    float bv = BF16_OUT ? bias[col] : 0.0f;
#pragma unroll
    for (int i = 0; i < 4; ++i) {
      int rowb = m0 + wm + i*16 + quad*4;
#pragma unroll
      for (int r = 0; r < 4; ++r) {
        float v = acc[i][j][r] + bv;
        if (BF16_OUT) ((u16*)Cout)[(size_t)(rowb+r)*N + col] = f2b(v);
        else          ((float*)Cout)[(size_t)(rowb+r)*N + col] = v;
      }
    }
  }
}

// ---------------- RoPE on K and V (reference ropes V too, not Q) ----------------
__global__ void rope_kernel(const u16* __restrict__ qkv, const float* __restrict__ fc,
                            const float* __restrict__ fs, u16* __restrict__ kout,
                            u16* __restrict__ vout) {
  int tid = threadIdx.x;
  int row = blockIdx.x;             // b*T + t
  int i = tid & 63, kv = tid >> 6;  // pair index, kv head
  int t = row & (T_SEQ-1);
  const u16* p = qkv + (size_t)row*QKVN + EMB + kv*HD + 2*i;
  float ka = b2f(p[0]),   kb = b2f(p[1]);
  float va = b2f(p[KVD]), vb = b2f(p[KVD+1]);
  float c = fc[t*64+i], s = fs[t*64+i];
  size_t ob = (size_t)row*KVD + kv*HD + 2*i;
  kout[ob]   = f2b(ka*c - kb*s);
  kout[ob+1] = f2b(ka*s + kb*c);
  vout[ob]   = f2b(va*c - vb*s);
  vout[ob+1] = f2b(va*s + vb*c);
}

// ---------------- V (b,t,kv,d) -> Vt (b,kv,d,t) ----------------
__global__ void transpose_v_kernel(const u16* __restrict__ vb, u16* __restrict__ vtb) {
  __shared__ u16 tile[32][33];
  int bkv = blockIdx.z;
  int b = bkv >> 2, kv = bkv & 3;
  int d0 = blockIdx.y*32, t0 = blockIdx.x*32;
  int tx = threadIdx.x, ty = threadIdx.y;
#pragma unroll
  for (int i = 0; i < 32; i += 8)
    tile[ty+i][tx] = vb[(size_t)(b*T_SEQ + t0+ty+i)*KVD + kv*HD + d0 + tx];
  __syncthreads();
#pragma unroll
  for (int i = 0; i < 32; i += 8)
    vtb[(size_t)(bkv*HD + d0+ty+i)*T_SEQ + t0 + tx] = tile[tx][ty+i];
}

// ---------------- flash attention v4: GQA-shared LDS staging ----------------
// One 256-thread block per (b, kv-group, 16-query tile). The 4 waves are the 4
// Q-heads sharing that KV group: identical trip counts (balanced barriers), 4x
// reuse of every staged K/V byte, no split-K (each wave owns its 16 queries).
// K-loop stages K-tile (64x128) + Vt-tile (128x64) via global_load_lds w=16.
// glds16 forbids LDS padding, so banking is fixed by an XOR swizzle of the 16B
// chunk index applied on the GLOBAL source address (read side XORs the same):
//   Ks row r (256B, 16 chunks): chunk cc holds global chunk cc^(r&15)
//   Vs row d (128B,  8 chunks): chunk cc holds global chunk cc^(d&7)
// Frag reads then spread uniformly over all 32 banks (8-cyc b128 floor).
__global__ __launch_bounds__(256, 3) void flash_kernel(const u16* __restrict__ qkv,
    const u16* __restrict__ kb, const u16* __restrict__ vtb, u16* __restrict__ yb) {
  constexpr int PP = 72;                 // P pitch: 144B rows, conflict-free pa reads
  __shared__ u16 Ks[64*128];             // 16 KB
  __shared__ u16 Vs[128*64];             // 16 KB
  __shared__ u16 Ps[4][16*PP];           // 9 KB
  const int tid = threadIdx.x;
  const int w = tid >> 6, lane = tid & 63;
  const int quad = lane >> 4, lc = lane & 15;
  const int bkv = blockIdx.x & 7;        // XCD-pinned (b,kv)
  const int r_  = blockIdx.x >> 3;       // 0..127
  const int b = bkv >> 2, kv = bkv & 3;
  const int h = kv*4 + w;                // wave = one head of the group
  const int qbase = (127 - r_)*16;       // heavy q-tiles dispatch first

  // Q frags (A-layout) for 16 queries of head h; no RoPE on Q
  bf16x8 qf[4];
  {
    const u16* qp = qkv + (size_t)(b*T_SEQ + qbase + lc)*QKVN + h*HD + quad*8;
#pragma unroll
    for (int ks = 0; ks < 4; ++ks) qf[ks] = ld_bf8(qp + ks*32);
  }

  f32x4 o[8] = {};
  float rs[4] = {0.f, 0.f, 0.f, 0.f};
  const u16* kbase = kb  + (size_t)b*T_SEQ*KVD + kv*HD;
  const u16* vbase = vtb + (size_t)bkv*HD*T_SEQ;
  const int nk = qbase + 16;
  const float cs = 0.08838834764831845f * 1.4426950408889634f;  // scale * log2(e)
  u16* pw = Ps[w];

  // per-lane swizzled chunk offsets (hoisted out of the K-loop)
  int koff[4], voff[2];
#pragma unroll
  for (int ks = 0; ks < 4; ++ks) koff[ks] = lc*128 + (((ks*4 + quad) ^ lc)*8);
#pragma unroll
  for (int ks = 0; ks < 2; ++ks) voff[ks] = lc*64 + (((ks*4 + quad) ^ (lc & 7))*8);

  for (int k0 = 0; k0 < nk; k0 += 64) {
    __syncthreads();
    // stage K tile: 1024 16B-chunks, 4 glds16/thread, source-side XOR swizzle
#pragma unroll
    for (int rr = 0; rr < 4; ++rr) {
      int krow = (rr*4 + w)*4 + (lane >> 4);
      int ccg  = (lane & 15) ^ (krow & 15);
      glds16(kbase + (size_t)(k0 + krow)*KVD + ccg*8, Ks + (size_t)(rr*4 + w)*512);
    }
    // stage Vt tile
#pragma unroll
    for (int rr = 0; rr < 4; ++rr) {
      int vrow = (rr*4 + w)*8 + (lane >> 3);
      int ccg  = (lane & 7) ^ (vrow & 7);
      glds16(vbase + (size_t)vrow*T_SEQ + k0 + ccg*8, Vs + (size_t)(rr*4 + w)*512);
    }
    __syncthreads();

    // S = Q K^T : 16 queries x 64 keys
    f32x4 sc[4] = {};
#pragma unroll
    for (int nt = 0; nt < 4; ++nt)
#pragma unroll
      for (int ks = 0; ks < 4; ++ks) {
        bf16x8 kf = ld_bf8(Ks + nt*16*128 + koff[ks]);
        sc[nt] = __builtin_amdgcn_mfma_f32_16x16x32_bf16(qf[ks], kf, sc[nt], 0, 0, 0);
      }

    // softmax (m=0): p = exp2(s*cs); mask only on the diagonal tile
    if (k0 + 63 > qbase) {
#pragma unroll
      for (int nt = 0; nt < 4; ++nt) {
        int key = k0 + nt*16 + lc;
        int qrow = qbase + quad*4;
#pragma unroll
        for (int r = 0; r < 4; ++r) {
          float p = (key <= qrow + r) ? exp2f(sc[nt][r]*cs) : 0.0f;
          rs[r] += p;
          pw[(quad*4 + r)*PP + nt*16 + lc] = f2b(p);
        }
      }
    } else {
#pragma unroll
      for (int nt = 0; nt < 4; ++nt)
#pragma unroll
        for (int r = 0; r < 4; ++r) {
          float p = exp2f(sc[nt][r]*cs);
          rs[r] += p;
          pw[(quad*4 + r)*PP + nt*16 + lc] = f2b(p);
        }
    }

    // P: C-layout -> A-layout via per-wave LDS roundtrip (intra-wave DS in-order)
    bf16x8 pa[2];
#pragma unroll
    for (int ks = 0; ks < 2; ++ks)
      pa[ks] = ld_bf8(pw + lc*PP + ks*32 + quad*8);

    // O += P V
#pragma unroll
    for (int j = 0; j < 8; ++j)
#pragma unroll
      for (int ks = 0; ks < 2; ++ks) {
        bf16x8 vf = ld_bf8(Vs + j*16*64 + voff[ks]);
        o[j] = __builtin_amdgcn_mfma_f32_16x16x32_bf16(pa[ks], vf, o[j], 0, 0, 0);
      }
  }

  // epilogue: l-reduce over the 16 key-lanes, normalize, store
#pragma unroll
  for (int r = 0; r < 4; ++r) {
    float v = rs[r];
#pragma unroll
    for (int off2 = 8; off2 >= 1; off2 >>= 1)
      v += __shfl_xor(v, off2);
    float inv = 1.0f / v;
    size_t orow = (size_t)(b*T_SEQ + qbase + quad*4 + r)*EMB + h*HD;
#pragma unroll
    for (int j = 0; j < 8; ++j)
      yb[orow + j*16 + lc] = f2b(o[j][r]*inv);
  }
}

extern "C" void kernel_launch(void* const* d_in, const int* in_sizes, int n_in,
                              void* d_out, int out_size, void* d_ws, size_t ws_size,
                              hipStream_t stream) {
  const float* x      = (const float*)d_in[0];
  const float* W_attn = (const float*)d_in[1];
  const float* b_attn = (const float*)d_in[2];
  const float* W_proj = (const float*)d_in[3];
  const float* fc     = (const float*)d_in[4];
  const float* fs     = (const float*)d_in[5];

  u16* ws   = (u16*)d_ws;
  u16* xb   = ws;                          // 8.39M elems  (later aliased by yb)
  u16* WaT  = xb   + (size_t)MROWS*EMB;    // 6.29M        (later aliased by WpT)
  u16* qkv  = WaT  + (size_t)QKVN*EMB;     // 12.58M
  u16* kbuf = qkv  + (size_t)MROWS*QKVN;   // 2.10M
  u16* vb   = kbuf + (size_t)MROWS*KVD;    // 2.10M
  u16* vtb  = vb   + (size_t)MROWS*KVD;    // 2.10M  -> total 67.1 MB
  u16* WpT  = WaT;   // W_attn^T dead after gemm1
  u16* yb   = xb;    // x_bf16 dead after gemm1
  float* out = (float*)d_out;

  cvt_x_kernel<<<(MROWS*EMB/4 + 255)/256, 256, 0, stream>>>(
      (const float4*)x, (ushort4*)xb, MROWS*EMB/4);
  transpose_w_kernel<<<dim3(QKVN/32, EMB/32), dim3(32, 8), 0, stream>>>(
      W_attn, WaT, EMB, QKVN);
  gemm_kernel<true><<<dim3(QKVN/128, MROWS/128), 256, 0, stream>>>(
      xb, WaT, b_attn, qkv, MROWS, QKVN, EMB);
  rope_kernel<<<MROWS, 256, 0, stream>>>(qkv, fc, fs, kbuf, vb);
  transpose_v_kernel<<<dim3(T_SEQ/32, HD/32, B_SZ*NKV), dim3(32, 8), 0, stream>>>(vb, vtb);
  transpose_w_kernel<<<dim3(EMB/32, EMB/32), dim3(32, 8), 0, stream>>>(
      W_proj, WpT, EMB, EMB);
  flash_kernel<<<dim3(B_SZ*NKV*(T_SEQ/16)), 256, 0, stream>>>(qkv, kbuf, vtb, yb);
  gemm_kernel<false><<<dim3(EMB/128, MROWS/128), 256, 0, stream>>>(
      yb, WpT, nullptr, out, MROWS, EMB, EMB);
}

// Round 5
// 307.753 us; speedup vs baseline: 1.7616x; 1.0226x over previous
//
#include <hip/hip_runtime.h>
#include <cstdint>
#include <cstddef>

#define T_SEQ 2048
#define B_SZ  2
#define EMB   2048
#define NH    16
#define NKV   4
#define HD    128
#define KVD   512
#define QKVN  3072
#define MROWS (B_SZ*T_SEQ)

typedef __bf16 bf16x8 __attribute__((ext_vector_type(8)));
typedef float  f32x4  __attribute__((ext_vector_type(4)));
typedef short  s16x8  __attribute__((ext_vector_type(8)));
typedef unsigned short u16;

__device__ __forceinline__ u16 f2b(float f) {
  uint32_t u = __builtin_bit_cast(uint32_t, f);
  u += 0x7fffu + ((u >> 16) & 1u);      // RNE
  return (u16)(u >> 16);
}
__device__ __forceinline__ float b2f(u16 h) {
  return __builtin_bit_cast(float, (uint32_t)h << 16);
}
__device__ __forceinline__ bf16x8 ld_bf8(const u16* p) {
  return __builtin_bit_cast(bf16x8, *(const s16x8*)p);
}
__device__ __forceinline__ void glds16(const void* g, void* l) {
  __builtin_amdgcn_global_load_lds((const __attribute__((address_space(1))) void*)g,
                                   (__attribute__((address_space(3))) void*)l, 16, 0, 0);
}

// ---------------- fp32 -> bf16 elementwise ----------------
__global__ void cvt_x_kernel(const float4* __restrict__ x, ushort4* __restrict__ xb, int n4) {
  int i = blockIdx.x*blockDim.x + threadIdx.x;
  if (i >= n4) return;
  float4 v = x[i];
  ushort4 o;
  o.x = f2b(v.x); o.y = f2b(v.y); o.z = f2b(v.z); o.w = f2b(v.w);
  xb[i] = o;
}

// ---------------- fp32 (R x C) -> bf16 transposed (C x R) ----------------
__global__ void transpose_w_kernel(const float* __restrict__ in, u16* __restrict__ out,
                                   int R, int C) {
  __shared__ float tile[32][33];
  int c0 = blockIdx.x*32, r0 = blockIdx.y*32;
  int tx = threadIdx.x, ty = threadIdx.y;
#pragma unroll
  for (int i = 0; i < 32; i += 8)
    tile[ty+i][tx] = in[(size_t)(r0+ty+i)*C + c0+tx];
  __syncthreads();
#pragma unroll
  for (int i = 0; i < 32; i += 8)
    out[(size_t)(c0+ty+i)*R + r0+tx] = f2b(tile[tx][ty+i]);
}

// ---------------- bf16 GEMM: C(MxN) = A(MxK) * Bt(NxK)^T (+bias) ----------------
// 128x128 tile, BK=64 (32 MFMA per barrier pair), 4 waves (2x2 of 64x64).
// LDS tiles use an XOR chunk swizzle: global 16B-chunk `pos` of row r lands at
// LDS pos `pos ^ (r&7)`; frag reads XOR the same. Read bank-starts become
// 4*((ks*4+quad)^(lc&7)) -> 8 distinct 4-bank groups, 2 lanes each per quad:
// every bank hit exactly 8x per wave64 b128 = conflict-free floor. Staging
// stays 128B-coalesced (permutation is within a cache line) and keeps the
// glds16 uniform-base+lane*16 requirement.
template<bool BF16_OUT>
__global__ __launch_bounds__(256) void gemm_kernel(const u16* __restrict__ A,
        const u16* __restrict__ Bt, const float* __restrict__ bias,
        void* __restrict__ Cout, int M, int N, int K) {
  __shared__ u16 As[128*64];
  __shared__ u16 Bs[128*64];
  const int tid = threadIdx.x;
  const int w = tid >> 6, lane = tid & 63;
  const int quad = lane >> 4, lc = lane & 15;
  const int m0 = blockIdx.y*128, n0 = blockIdx.x*128;
  const int wm = (w >> 1)*64, wn = (w & 1)*64;
  f32x4 acc[4][4] = {};
  // frag-read chunk offsets (row&7 == lc&7 since wm,wn,i*16 are 0 mod 8)
  int xoff[2];
#pragma unroll
  for (int ks = 0; ks < 2; ++ks) xoff[ks] = ((ks*4 + quad) ^ (lc & 7))*8;
  // staging source chunk positions (chunk id c = r*256 + tid)
  int srow[4], spos[4];
#pragma unroll
  for (int r = 0; r < 4; ++r) {
    int c = r*256 + tid;
    srow[r] = c >> 3;
    spos[r] = ((c & 7) ^ (srow[r] & 7))*8;
  }
  for (int k0 = 0; k0 < K; k0 += 64) {
    __syncthreads();
#pragma unroll
    for (int r = 0; r < 4; ++r) {
      glds16(A  + (size_t)(m0+srow[r])*K + k0 + spos[r], As + (size_t)(r*256 + w*64)*8);
      glds16(Bt + (size_t)(n0+srow[r])*K + k0 + spos[r], Bs + (size_t)(r*256 + w*64)*8);
    }
    __syncthreads();
#pragma unroll
    for (int ks = 0; ks < 2; ++ks) {
      bf16x8 af[4], bfr[4];
#pragma unroll
      for (int i = 0; i < 4; ++i) af[i]  = ld_bf8(As + (wm + i*16 + lc)*64 + xoff[ks]);
#pragma unroll
      for (int j = 0; j < 4; ++j) bfr[j] = ld_bf8(Bs + (wn + j*16 + lc)*64 + xoff[ks]);
#pragma unroll
      for (int i = 0; i < 4; ++i)
#pragma unroll
        for (int j = 0; j < 4; ++j)
          acc[i][j] = __builtin_amdgcn_mfma_f32_16x16x32_bf16(af[i], bfr[j], acc[i][j], 0, 0, 0);
    }
  }
#pragma unroll
  for (int j = 0; j < 4; ++j) {
    int col = n0 + wn + j*16 + lc;
    float bv = BF16_OUT ? bias[col] : 0.0f;
#pragma unroll
    for (int i = 0; i < 4; ++i) {
      int rowb = m0 + wm + i*16 + quad*4;
#pragma unroll
      for (int r = 0; r < 4; ++r) {
        float v = acc[i][j][r] + bv;
        if (BF16_OUT) ((u16*)Cout)[(size_t)(rowb+r)*N + col] = f2b(v);
        else          ((float*)Cout)[(size_t)(rowb+r)*N + col] = v;
      }
    }
  }
}

// ---------------- RoPE on K and V (reference ropes V too, not Q) ----------------
__global__ void rope_kernel(const u16* __restrict__ qkv, const float* __restrict__ fc,
                            const float* __restrict__ fs, u16* __restrict__ kout,
                            u16* __restrict__ vout) {
  int tid = threadIdx.x;
  int row = blockIdx.x;             // b*T + t
  int i = tid & 63, kv = tid >> 6;  // pair index, kv head
  int t = row & (T_SEQ-1);
  const u16* p = qkv + (size_t)row*QKVN + EMB + kv*HD + 2*i;
  float ka = b2f(p[0]),   kb = b2f(p[1]);
  float va = b2f(p[KVD]), vb = b2f(p[KVD+1]);
  float c = fc[t*64+i], s = fs[t*64+i];
  size_t ob = (size_t)row*KVD + kv*HD + 2*i;
  kout[ob]   = f2b(ka*c - kb*s);
  kout[ob+1] = f2b(ka*s + kb*c);
  vout[ob]   = f2b(va*c - vb*s);
  vout[ob+1] = f2b(va*s + vb*c);
}

// ---------------- V (b,t,kv,d) -> Vt (b,kv,d,t) ----------------
__global__ void transpose_v_kernel(const u16* __restrict__ vb, u16* __restrict__ vtb) {
  __shared__ u16 tile[32][33];
  int bkv = blockIdx.z;
  int b = bkv >> 2, kv = bkv & 3;
  int d0 = blockIdx.y*32, t0 = blockIdx.x*32;
  int tx = threadIdx.x, ty = threadIdx.y;
#pragma unroll
  for (int i = 0; i < 32; i += 8)
    tile[ty+i][tx] = vb[(size_t)(b*T_SEQ + t0+ty+i)*KVD + kv*HD + d0 + tx];
  __syncthreads();
#pragma unroll
  for (int i = 0; i < 32; i += 8)
    vtb[(size_t)(bkv*HD + d0+ty+i)*T_SEQ + t0 + tx] = tile[tx][ty+i];
}

// ---------------- flash attention v4: GQA-shared LDS staging ----------------
// One 256-thread block per (b, kv-group, 16-query tile). The 4 waves are the 4
// Q-heads sharing that KV group: identical trip counts (balanced barriers), 4x
// reuse of every staged K/V byte, no split-K (each wave owns its 16 queries).
__global__ __launch_bounds__(256, 3) void flash_kernel(const u16* __restrict__ qkv,
    const u16* __restrict__ kb, const u16* __restrict__ vtb, u16* __restrict__ yb) {
  constexpr int PP = 72;                 // P pitch: 144B rows, conflict-free pa reads
  __shared__ u16 Ks[64*128];             // 16 KB
  __shared__ u16 Vs[128*64];             // 16 KB
  __shared__ u16 Ps[4][16*PP];           // 9 KB
  const int tid = threadIdx.x;
  const int w = tid >> 6, lane = tid & 63;
  const int quad = lane >> 4, lc = lane & 15;
  const int bkv = blockIdx.x & 7;        // XCD-pinned (b,kv)
  const int r_  = blockIdx.x >> 3;       // 0..127
  const int b = bkv >> 2, kv = bkv & 3;
  const int h = kv*4 + w;                // wave = one head of the group
  const int qbase = (127 - r_)*16;       // heavy q-tiles dispatch first

  // Q frags (A-layout) for 16 queries of head h; no RoPE on Q
  bf16x8 qf[4];
  {
    const u16* qp = qkv + (size_t)(b*T_SEQ + qbase + lc)*QKVN + h*HD + quad*8;
#pragma unroll
    for (int ks = 0; ks < 4; ++ks) qf[ks] = ld_bf8(qp + ks*32);
  }

  f32x4 o[8] = {};
  float rs[4] = {0.f, 0.f, 0.f, 0.f};
  const u16* kbase = kb  + (size_t)b*T_SEQ*KVD + kv*HD;
  const u16* vbase = vtb + (size_t)bkv*HD*T_SEQ;
  const int nk = qbase + 16;
  const float cs = 0.08838834764831845f * 1.4426950408889634f;  // scale * log2(e)
  u16* pw = Ps[w];

  // per-lane swizzled chunk offsets (hoisted out of the K-loop)
  int koff[4], voff[2];
#pragma unroll
  for (int ks = 0; ks < 4; ++ks) koff[ks] = lc*128 + (((ks*4 + quad) ^ lc)*8);
#pragma unroll
  for (int ks = 0; ks < 2; ++ks) voff[ks] = lc*64 + (((ks*4 + quad) ^ (lc & 7))*8);

  for (int k0 = 0; k0 < nk; k0 += 64) {
    __syncthreads();
    // stage K tile: 1024 16B-chunks, 4 glds16/thread, source-side XOR swizzle
#pragma unroll
    for (int rr = 0; rr < 4; ++rr) {
      int krow = (rr*4 + w)*4 + (lane >> 4);
      int ccg  = (lane & 15) ^ (krow & 15);
      glds16(kbase + (size_t)(k0 + krow)*KVD + ccg*8, Ks + (size_t)(rr*4 + w)*512);
    }
    // stage Vt tile
#pragma unroll
    for (int rr = 0; rr < 4; ++rr) {
      int vrow = (rr*4 + w)*8 + (lane >> 3);
      int ccg  = (lane & 7) ^ (vrow & 7);
      glds16(vbase + (size_t)vrow*T_SEQ + k0 + ccg*8, Vs + (size_t)(rr*4 + w)*512);
    }
    __syncthreads();

    // S = Q K^T : 16 queries x 64 keys
    f32x4 sc[4] = {};
#pragma unroll
    for (int nt = 0; nt < 4; ++nt)
#pragma unroll
      for (int ks = 0; ks < 4; ++ks) {
        bf16x8 kf = ld_bf8(Ks + nt*16*128 + koff[ks]);
        sc[nt] = __builtin_amdgcn_mfma_f32_16x16x32_bf16(qf[ks], kf, sc[nt], 0, 0, 0);
      }

    // softmax (m=0): p = exp2(s*cs); mask only on the diagonal tile
    if (k0 + 63 > qbase) {
#pragma unroll
      for (int nt = 0; nt < 4; ++nt) {
        int key = k0 + nt*16 + lc;
        int qrow = qbase + quad*4;
#pragma unroll
        for (int r = 0; r < 4; ++r) {
          float p = (key <= qrow + r) ? exp2f(sc[nt][r]*cs) : 0.0f;
          rs[r] += p;
          pw[(quad*4 + r)*PP + nt*16 + lc] = f2b(p);
        }
      }
    } else {
#pragma unroll
      for (int nt = 0; nt < 4; ++nt)
#pragma unroll
        for (int r = 0; r < 4; ++r) {
          float p = exp2f(sc[nt][r]*cs);
          rs[r] += p;
          pw[(quad*4 + r)*PP + nt*16 + lc] = f2b(p);
        }
    }

    // P: C-layout -> A-layout via per-wave LDS roundtrip (intra-wave DS in-order)
    bf16x8 pa[2];
#pragma unroll
    for (int ks = 0; ks < 2; ++ks)
      pa[ks] = ld_bf8(pw + lc*PP + ks*32 + quad*8);

    // O += P V
#pragma unroll
    for (int j = 0; j < 8; ++j)
#pragma unroll
      for (int ks = 0; ks < 2; ++ks) {
        bf16x8 vf = ld_bf8(Vs + j*16*64 + voff[ks]);
        o[j] = __builtin_amdgcn_mfma_f32_16x16x32_bf16(pa[ks], vf, o[j], 0, 0, 0);
      }
  }

  // epilogue: l-reduce over the 16 key-lanes, normalize, store
#pragma unroll
  for (int r = 0; r < 4; ++r) {
    float v = rs[r];
#pragma unroll
    for (int off2 = 8; off2 >= 1; off2 >>= 1)
      v += __shfl_xor(v, off2);
    float inv = 1.0f / v;
    size_t orow = (size_t)(b*T_SEQ + qbase + quad*4 + r)*EMB + h*HD;
#pragma unroll
    for (int j = 0; j < 8; ++j)
      yb[orow + j*16 + lc] = f2b(o[j][r]*inv);
  }
}

extern "C" void kernel_launch(void* const* d_in, const int* in_sizes, int n_in,
                              void* d_out, int out_size, void* d_ws, size_t ws_size,
                              hipStream_t stream) {
  const float* x      = (const float*)d_in[0];
  const float* W_attn = (const float*)d_in[1];
  const float* b_attn = (const float*)d_in[2];
  const float* W_proj = (const float*)d_in[3];
  const float* fc     = (const float*)d_in[4];
  const float* fs     = (const float*)d_in[5];

  u16* ws   = (u16*)d_ws;
  u16* xb   = ws;                          // 8.39M elems  (later aliased by yb)
  u16* WaT  = xb   + (size_t)MROWS*EMB;    // 6.29M        (later aliased by WpT)
  u16* qkv  = WaT  + (size_t)QKVN*EMB;     // 12.58M
  u16* kbuf = qkv  + (size_t)MROWS*QKVN;   // 2.10M
  u16* vb   = kbuf + (size_t)MROWS*KVD;    // 2.10M
  u16* vtb  = vb   + (size_t)MROWS*KVD;    // 2.10M  -> total 67.1 MB
  u16* WpT  = WaT;   // W_attn^T dead after gemm1
  u16* yb   = xb;    // x_bf16 dead after gemm1
  float* out = (float*)d_out;

  cvt_x_kernel<<<(MROWS*EMB/4 + 255)/256, 256, 0, stream>>>(
      (const float4*)x, (ushort4*)xb, MROWS*EMB/4);
  transpose_w_kernel<<<dim3(QKVN/32, EMB/32), dim3(32, 8), 0, stream>>>(
      W_attn, WaT, EMB, QKVN);
  gemm_kernel<true><<<dim3(QKVN/128, MROWS/128), 256, 0, stream>>>(
      xb, WaT, b_attn, qkv, MROWS, QKVN, EMB);
  rope_kernel<<<MROWS, 256, 0, stream>>>(qkv, fc, fs, kbuf, vb);
  transpose_v_kernel<<<dim3(T_SEQ/32, HD/32, B_SZ*NKV), dim3(32, 8), 0, stream>>>(vb, vtb);
  transpose_w_kernel<<<dim3(EMB/32, EMB/32), dim3(32, 8), 0, stream>>>(
      W_proj, WpT, EMB, EMB);
  flash_kernel<<<dim3(B_SZ*NKV*(T_SEQ/16)), 256, 0, stream>>>(qkv, kbuf, vtb, yb);
  gemm_kernel<false><<<dim3(EMB/128, MROWS/128), 256, 0, stream>>>(
      yb, WpT, nullptr, out, MROWS, EMB, EMB);
}